// Round 1
// baseline (1056.307 us; speedup 1.0000x reference)
//
#include <hip/hip_runtime.h>
#include <hip/hip_bf16.h>

#define NE 512

// ---------------- static device buffers (avoid d_ws dependence) ----------------
__device__ __align__(16) float g_p[2][NE*NE*64];     // ping-pong pair features (67MB each)
__device__ __align__(16) float g_sv0[NE*64];
__device__ __align__(16) float g_sv[2][NE*256];
__device__ __align__(16) float g_pu4[NE*4];
__device__ __align__(16) float g_pd4[NE*4];
__device__ __align__(16) float g_pu[NE*64];
__device__ __align__(16) float g_pd[NE*64];
__device__ __align__(16) float g_su0[64];
__device__ __align__(16) float g_sd0[64];
__device__ __align__(16) float g_su[256];
__device__ __align__(16) float g_sd[256];
__device__ __align__(16) float g_part[8*NE*64];      // per-(j,chunk) partial means of p
__device__ __align__(16) float g_f[NE];              // sum_a exp(-|r_i - a|)
__device__ __align__(16) float g_hu[256*256];
__device__ __align__(16) float g_hd[256*256];
__device__ __align__(16) float g_orbu[256*256];
__device__ __align__(16) float g_orbd[256*256];
__device__ float g_logs[2];

__device__ __forceinline__ float tanh_fast(float x) {
  float e = __expf(2.f * x);
  return 1.f - 2.f / (e + 1.f);
}

// ---------------- K0: geometry -> s_v0, f, su0/sd0 ----------------
__global__ __launch_bounds__(512) void k_geom(const float* __restrict__ r,
                                              const float* __restrict__ a) {
  int e = threadIdx.x;
  float rx = r[3*e], ry = r[3*e+1], rz = r[3*e+2];
  float facc = 0.f;
  #pragma unroll
  for (int at = 0; at < 16; ++at) {
    float dx = rx - a[3*at], dy = ry - a[3*at+1], dz = rz - a[3*at+2];
    float len = sqrtf(dx*dx + dy*dy + dz*dz);
    g_sv0[e*64 + 4*at + 0] = dx;
    g_sv0[e*64 + 4*at + 1] = dy;
    g_sv0[e*64 + 4*at + 2] = dz;
    g_sv0[e*64 + 4*at + 3] = len;
    facc += expf(-len);
  }
  g_f[e] = facc;
  __syncthreads();            // global writes visible within block after barrier
  if (e < 128) {
    int h = e >> 6, c = e & 63;
    float s = 0.f;
    for (int i = 0; i < 256; ++i) s += g_sv0[(h*256 + i)*64 + c];
    (h ? g_sd0 : g_su0)[c] = s * (1.f/256.f);
  }
}

// ---------------- K0b: means of p0 (4-dim geometry pairs) ----------------
__global__ __launch_bounds__(256) void k_pmean0(const float* __restrict__ r) {
  int j = blockIdx.x, t = threadIdx.x;
  float rjx = r[3*j], rjy = r[3*j+1], rjz = r[3*j+2];
  __shared__ float red[4][4];
  for (int h = 0; h < 2; ++h) {
    int i = h*256 + t;
    float dx = rjx - r[3*i], dy = rjy - r[3*i+1], dz = rjz - r[3*i+2];
    float ee = (i == j) ? 1.f : 0.f;
    float ex = dx+ee, ey = dy+ee, ez = dz+ee;
    float len = sqrtf(ex*ex + ey*ey + ez*ez);
    float v0 = dx, v1 = dy, v2 = dz, v3 = len;
    #pragma unroll
    for (int m = 1; m < 64; m <<= 1) {
      v0 += __shfl_xor(v0, m); v1 += __shfl_xor(v1, m);
      v2 += __shfl_xor(v2, m); v3 += __shfl_xor(v3, m);
    }
    if ((t & 63) == 0) {
      int wv = t >> 6;
      red[wv][0]=v0; red[wv][1]=v1; red[wv][2]=v2; red[wv][3]=v3;
    }
    __syncthreads();
    if (t == 0) {
      float* dst = h ? g_pd4 : g_pu4;
      #pragma unroll
      for (int c = 0; c < 4; ++c)
        dst[j*4 + c] = (red[0][c]+red[1][c]+red[2][c]+red[3][c]) * (1.f/256.f);
    }
    __syncthreads();
  }
}

// ---------------- p-channel update. MODE 0: from geometry; 1: load+store; 2: load only ----
template<int MODE>
__global__ __launch_bounds__(256) void k_pup(const float* __restrict__ W,
                                             const float* __restrict__ Wb,
                                             const float* __restrict__ r,
                                             int src, int dst) {
  __shared__ __align__(16) float psh[4][64];
  int t = threadIdx.x, lane = t & 63, wv = t >> 6;
  int gw = blockIdx.x*4 + wv;          // 0..4095
  int j = gw >> 3, chunk = gw & 7;
  int i0 = chunk * 64;
  float macc = 0.f;
  if (MODE == 0) {
    float w0 = W[lane], w1 = W[64+lane], w2 = W[128+lane], w3 = W[192+lane];
    float bb = Wb[lane];
    float rjx = r[3*j], rjy = r[3*j+1], rjz = r[3*j+2];
    float* pout = g_p[0];
    for (int ii = 0; ii < 64; ++ii) {
      int i = i0 + ii;
      float dx = rjx - r[3*i], dy = rjy - r[3*i+1], dz = rjz - r[3*i+2];
      float ee = (i == j) ? 1.f : 0.f;
      float ex = dx+ee, ey = dy+ee, ez = dz+ee;
      float len = sqrtf(ex*ex + ey*ey + ez*ez);
      float y = tanh_fast(bb + dx*w0 + dy*w1 + dz*w2 + len*w3);
      pout[(i*NE + j)*64 + lane] = y;
      macc += y;
    }
  } else {
    const float* pin = g_p[src];
    float* pout = g_p[dst];
    float wcol[64];
    #pragma unroll
    for (int k = 0; k < 64; ++k) wcol[k] = W[k*64 + lane];
    float bb = Wb[lane];
    for (int ii = 0; ii < 64; ++ii) {
      int i = i0 + ii;
      int base = (i*NE + j)*64;
      float x = pin[base + lane];
      psh[wv][lane] = x;
      float acc = bb;
      #pragma unroll
      for (int g = 0; g < 16; ++g) {
        float4 pv = *(const float4*)&psh[wv][4*g];   // wave-uniform broadcast reads
        acc += pv.x*wcol[4*g] + pv.y*wcol[4*g+1] + pv.z*wcol[4*g+2] + pv.w*wcol[4*g+3];
      }
      float y = tanh_fast(acc) + x;                  // residual (layers >= 1)
      if (MODE == 1) pout[base + lane] = y;
      macc += y;
    }
  }
  g_part[chunk*(NE*64) + j*64 + lane] = macc;
}

// ---------------- finalize p-means + s-means ----------------
__global__ __launch_bounds__(256) void k_reduce(int svsel) {
  int bid = blockIdx.x, t = threadIdx.x;
  if (bid < 256) {
    int idx = bid*256 + t;
    int half = idx >> 15, rem = idx & 32767;
    int j = rem >> 6, l = rem & 63;
    const float* pp = g_part + half*(4*NE*64);
    float s = pp[0*(NE*64)+j*64+l] + pp[1*(NE*64)+j*64+l]
            + pp[2*(NE*64)+j*64+l] + pp[3*(NE*64)+j*64+l];
    (half ? g_pd : g_pu)[j*64 + l] = s * (1.f/256.f);
  } else {
    int h = bid - 256;
    const float* sv = g_sv[svsel];
    float s = 0.f;
    for (int i = 0; i < 256; ++i) s += sv[(h*256 + i)*256 + t];
    (h ? g_sd : g_su)[t] = s * (1.f/256.f);
  }
}

// ---------------- generic s-channel matmul (layers / heads / orbitals) ----------------
// which: 0=layer0, 1..3=layer l, 4=head_u, 5=head_d, 6=orb_u, 7=orb_d
template<int PUK, int SVK, int MEANK>
__global__ __launch_bounds__(256) void k_smm(int which, const float* __restrict__ W,
                                             const float* __restrict__ Wb) {
  constexpr int MAINK = 2*PUK + SVK;
  __shared__ __align__(16) float wsl[MAINK*32];
  __shared__ float insl[32*(MAINK+1)];
  __shared__ float biasv[32];
  __shared__ float bred[256];
  const float *pu_p=nullptr, *pd_p=nullptr, *sv_p=nullptr, *su_p=nullptr, *sd_p=nullptr;
  const float *res_p=nullptr, *rs_p=nullptr;
  float* out_p = nullptr;
  int row0 = 0, dotanh = 1;
  switch (which) {
    case 0: pu_p=g_pu4; pd_p=g_pd4; su_p=g_su0; sd_p=g_sd0; sv_p=g_sv0; out_p=g_sv[0]; break;
    case 1: case 2: case 3:
      pu_p=g_pu; pd_p=g_pd; su_p=g_su; sd_p=g_sd;
      sv_p=g_sv[(which+1)&1]; res_p=sv_p; out_p=g_sv[which&1]; break;
    case 4: pu_p=g_pu; pd_p=g_pd; su_p=g_su; sd_p=g_sd; sv_p=g_sv[1]; out_p=g_hu; break;
    case 5: pu_p=g_pu; pd_p=g_pd; su_p=g_su; sd_p=g_sd; sv_p=g_sv[1]; out_p=g_hd; row0=256; break;
    case 6: sv_p=g_hu; out_p=g_orbu; rs_p=g_f;       dotanh=0; break;
    default: sv_p=g_hd; out_p=g_orbd; rs_p=g_f+256;  dotanh=0; break;
  }
  int t = threadIdx.x;
  int rg = blockIdx.x, cg = blockIdx.y;
  int col0 = cg * 32;
  for (int idx = t; idx < MAINK*32; idx += 256) {
    int c = idx >> 5, cl = idx & 31;
    wsl[idx] = W[(2*MEANK + c)*256 + col0 + cl];
  }
  for (int rr = 0; rr < 32; ++rr) {
    int row = row0 + rg*32 + rr;
    for (int c = t; c < MAINK; c += 256) {
      float v;
      if (c < PUK) v = pu_p[row*PUK + c];
      else if (c < 2*PUK) v = pd_p[row*PUK + (c - PUK)];
      else v = sv_p[row*SVK + (c - 2*PUK)];
      insl[rr*(MAINK+1) + c] = v;
    }
  }
  {
    int pcol = t & 31, ps = t >> 5;
    float bacc = 0.f;
    if (MEANK > 0) {
      for (int c = ps; c < MEANK; c += 8)
        bacc += su_p[c]*W[c*256 + col0 + pcol] + sd_p[c]*W[(MEANK + c)*256 + col0 + pcol];
    }
    bred[ps*32 + pcol] = bacc;
  }
  __syncthreads();
  if (t < 32) {
    float s = Wb[col0 + t];
    #pragma unroll
    for (int p8 = 0; p8 < 8; ++p8) s += bred[p8*32 + t];
    biasv[t] = s;
  }
  __syncthreads();
  int c4 = t & 7, rl = t >> 3;
  float a0 = biasv[4*c4], a1 = biasv[4*c4+1], a2 = biasv[4*c4+2], a3 = biasv[4*c4+3];
  const float* inrow = &insl[rl*(MAINK+1)];
  for (int c = 0; c < MAINK; ++c) {
    float iv = inrow[c];
    float4 wv = *(const float4*)&wsl[c*32 + 4*c4];
    a0 += iv*wv.x; a1 += iv*wv.y; a2 += iv*wv.z; a3 += iv*wv.w;
  }
  int rowA = rg*32 + rl;
  int col = col0 + 4*c4;
  if (dotanh) { a0=tanh_fast(a0); a1=tanh_fast(a1); a2=tanh_fast(a2); a3=tanh_fast(a3); }
  if (res_p) {
    float4 rv = *(const float4*)&res_p[rowA*256 + col];
    a0 += rv.x; a1 += rv.y; a2 += rv.z; a3 += rv.w;
  }
  if (rs_p) { float fsc = rs_p[rowA]; a0*=fsc; a1*=fsc; a2*=fsc; a3*=fsc; }
  float4 ov; ov.x=a0; ov.y=a1; ov.z=a2; ov.w=a3;
  *(float4*)&out_p[rowA*256 + col] = ov;
}

// ---------------- register-resident LU with implicit partial pivoting ----------------
__global__ __launch_bounds__(512) void k_lu() {
  __shared__ float colbuf[256];
  __shared__ float used[256];
  __shared__ __align__(16) float prow[256];
  const float* A = (blockIdx.x == 0) ? g_orbu : g_orbd;
  int t = threadIdx.x;
  int q = t >> 8;            // column half: [128q, 128q+127]
  int r = t & 255;           // row
  int lane = t & 63;
  float4 av[32];
  const float4* Ar = (const float4*)(A + r*256 + q*128);
  #pragma unroll
  for (int g = 0; g < 32; ++g) av[g] = Ar[g];
  if (t < 256) used[t] = 0.f;
  if (q == 0) colbuf[r] = av[0].x;
  __syncthreads();
  float logsum = 0.f;
  for (int k = 0; k < 256; ++k) {
    // phase A: redundant per-wave pivot search over unused rows
    float4 cv = *(const float4*)&colbuf[4*lane];
    float4 uv = *(const float4*)&used[4*lane];
    float b0 = (uv.x != 0.f) ? -1.f : fabsf(cv.x);
    float b1 = (uv.y != 0.f) ? -1.f : fabsf(cv.y);
    float b2 = (uv.z != 0.f) ? -1.f : fabsf(cv.z);
    float b3 = (uv.w != 0.f) ? -1.f : fabsf(cv.w);
    float bb = b0; int bi = 4*lane;
    if (b1 > bb) { bb = b1; bi = 4*lane+1; }
    if (b2 > bb) { bb = b2; bi = 4*lane+2; }
    if (b3 > bb) { bb = b3; bi = 4*lane+3; }
    #pragma unroll
    for (int m = 1; m < 64; m <<= 1) {
      float ob = __shfl_xor(bb, m);
      int   oi = __shfl_xor(bi, m);
      if (ob > bb || (ob == bb && oi < bi)) { bb = ob; bi = oi; }
    }
    int p = bi;
    float piv = colbuf[p];
    logsum += logf(bb);
    float multv = colbuf[r] / piv;
    bool alive = (q*128 + 127) > k;
    if (alive && r == p) {
      #pragma unroll
      for (int g = 0; g < 32; ++g) *(float4*)&prow[q*128 + 4*g] = av[g];
    }
    __syncthreads();
    // phase B: rank-1 update; owner half extracts column k+1
    if (alive) {
      #pragma unroll
      for (int g = 0; g < 32; ++g) {
        float4 pr = *(const float4*)&prow[q*128 + 4*g];
        av[g].x -= multv*pr.x; av[g].y -= multv*pr.y;
        av[g].z -= multv*pr.z; av[g].w -= multv*pr.w;
      }
      int kn = k + 1;
      if (kn < 256 && (kn >> 7) == q) {
        int gsel = (kn & 127) >> 2;
        float4 s = av[0];
        #pragma unroll
        for (int g = 1; g < 32; ++g) if (g == gsel) s = av[g];
        int cc = kn & 3;
        float val = cc==0 ? s.x : cc==1 ? s.y : cc==2 ? s.z : s.w;
        colbuf[r] = val;
      }
    }
    if (r == p && t < 256) used[p] = 1.f;
    __syncthreads();
  }
  if (t == 0) g_logs[blockIdx.x] = logsum;
}

__global__ void k_final(float* out) { out[0] = g_logs[0] + g_logs[1]; }

// ---------------- launch ----------------
extern "C" void kernel_launch(void* const* d_in, const int* in_sizes, int n_in,
                              void* d_out, int out_size, void* d_ws, size_t ws_size,
                              hipStream_t stream) {
  const float* r     = (const float*)d_in[0];
  const float* a     = (const float*)d_in[1];
  const float* V0_W  = (const float*)d_in[2];
  const float* V0_b  = (const float*)d_in[3];
  const float* Vr_W  = (const float*)d_in[4];
  const float* Vr_b  = (const float*)d_in[5];
  const float* W0_W  = (const float*)d_in[6];
  const float* W0_b  = (const float*)d_in[7];
  const float* Wr_W  = (const float*)d_in[8];
  const float* Wr_b  = (const float*)d_in[9];
  const float* Vhu_W = (const float*)d_in[10];
  const float* Vhu_b = (const float*)d_in[11];
  const float* Vhd_W = (const float*)d_in[12];
  const float* Vhd_b = (const float*)d_in[13];
  const float* wu_W  = (const float*)d_in[14];
  const float* wu_b  = (const float*)d_in[15];
  const float* wd_W  = (const float*)d_in[16];
  const float* wd_b  = (const float*)d_in[17];
  float* out = (float*)d_out;

  k_geom<<<1, 512, 0, stream>>>(r, a);
  k_pmean0<<<512, 256, 0, stream>>>(r);

  // layer 0
  k_smm<4,64,64><<<dim3(16,8), 256, 0, stream>>>(0, V0_W, V0_b);
  k_pup<0><<<1024, 256, 0, stream>>>(W0_W, W0_b, r, 0, 0);
  k_reduce<<<258, 256, 0, stream>>>(0);
  // layer 1
  k_smm<64,256,256><<<dim3(16,8), 256, 0, stream>>>(1, Vr_W + 0*896*256, Vr_b + 0);
  k_pup<1><<<1024, 256, 0, stream>>>(Wr_W + 0*4096, Wr_b + 0, r, 0, 1);
  k_reduce<<<258, 256, 0, stream>>>(1);
  // layer 2
  k_smm<64,256,256><<<dim3(16,8), 256, 0, stream>>>(2, Vr_W + 1*896*256, Vr_b + 256);
  k_pup<1><<<1024, 256, 0, stream>>>(Wr_W + 1*4096, Wr_b + 64, r, 1, 0);
  k_reduce<<<258, 256, 0, stream>>>(0);
  // layer 3 (p4 not stored; only its means)
  k_smm<64,256,256><<<dim3(16,8), 256, 0, stream>>>(3, Vr_W + 2*896*256, Vr_b + 512);
  k_pup<2><<<1024, 256, 0, stream>>>(Wr_W + 2*4096, Wr_b + 128, r, 0, 0);
  k_reduce<<<258, 256, 0, stream>>>(1);
  // heads
  k_smm<64,256,256><<<dim3(8,8), 256, 0, stream>>>(4, Vhu_W, Vhu_b);
  k_smm<64,256,256><<<dim3(8,8), 256, 0, stream>>>(5, Vhd_W, Vhd_b);
  // orbitals
  k_smm<0,256,0><<<dim3(8,8), 256, 0, stream>>>(6, wu_W, wu_b);
  k_smm<0,256,0><<<dim3(8,8), 256, 0, stream>>>(7, wd_W, wd_b);
  // log|det| x2 and combine
  k_lu<<<2, 512, 0, stream>>>();
  k_final<<<1, 1, 0, stream>>>(out);
}

// Round 2
// 1014.156 us; speedup vs baseline: 1.0416x; 1.0416x over previous
//
#include <hip/hip_runtime.h>
#include <hip/hip_bf16.h>

#define NE 512

// ---------------- static device buffers (avoid d_ws dependence) ----------------
__device__ __align__(16) float g_p[2][NE*NE*64];     // ping-pong pair features (67MB each)
__device__ __align__(16) float g_sv0[NE*64];
__device__ __align__(16) float g_sv[2][NE*256];
__device__ __align__(16) float g_pu4[NE*4];
__device__ __align__(16) float g_pd4[NE*4];
__device__ __align__(16) float g_pu[NE*64];
__device__ __align__(16) float g_pd[NE*64];
__device__ __align__(16) float g_su0[64];
__device__ __align__(16) float g_sd0[64];
__device__ __align__(16) float g_su[256];
__device__ __align__(16) float g_sd[256];
__device__ __align__(16) float g_part[8*NE*64];      // per-(j,chunk) partial means of p
__device__ __align__(16) float g_f[NE];              // sum_a exp(-|r_i - a|)
__device__ __align__(16) float g_hu[256*256];
__device__ __align__(16) float g_hd[256*256];
__device__ __align__(16) float g_orbu[256*256];
__device__ __align__(16) float g_orbd[256*256];
__device__ float g_logs[2];

__device__ __forceinline__ float tanh_fast(float x) {
  float e = __expf(2.f * x);
  return 1.f - 2.f / (e + 1.f);
}

// ---------------- K0: geometry -> s_v0, f, su0/sd0 ----------------
__global__ __launch_bounds__(512) void k_geom(const float* __restrict__ r,
                                              const float* __restrict__ a) {
  int e = threadIdx.x;
  float rx = r[3*e], ry = r[3*e+1], rz = r[3*e+2];
  float facc = 0.f;
  #pragma unroll
  for (int at = 0; at < 16; ++at) {
    float dx = rx - a[3*at], dy = ry - a[3*at+1], dz = rz - a[3*at+2];
    float len = sqrtf(dx*dx + dy*dy + dz*dz);
    g_sv0[e*64 + 4*at + 0] = dx;
    g_sv0[e*64 + 4*at + 1] = dy;
    g_sv0[e*64 + 4*at + 2] = dz;
    g_sv0[e*64 + 4*at + 3] = len;
    facc += expf(-len);
  }
  g_f[e] = facc;
  __syncthreads();            // global writes visible within block after barrier
  if (e < 128) {
    int h = e >> 6, c = e & 63;
    float s = 0.f;
    for (int i = 0; i < 256; ++i) s += g_sv0[(h*256 + i)*64 + c];
    (h ? g_sd0 : g_su0)[c] = s * (1.f/256.f);
  }
}

// ---------------- K0b: means of p0 (4-dim geometry pairs) ----------------
__global__ __launch_bounds__(256) void k_pmean0(const float* __restrict__ r) {
  int j = blockIdx.x, t = threadIdx.x;
  float rjx = r[3*j], rjy = r[3*j+1], rjz = r[3*j+2];
  __shared__ float red[4][4];
  for (int h = 0; h < 2; ++h) {
    int i = h*256 + t;
    float dx = rjx - r[3*i], dy = rjy - r[3*i+1], dz = rjz - r[3*i+2];
    float ee = (i == j) ? 1.f : 0.f;
    float ex = dx+ee, ey = dy+ee, ez = dz+ee;
    float len = sqrtf(ex*ex + ey*ey + ez*ez);
    float v0 = dx, v1 = dy, v2 = dz, v3 = len;
    #pragma unroll
    for (int m = 1; m < 64; m <<= 1) {
      v0 += __shfl_xor(v0, m); v1 += __shfl_xor(v1, m);
      v2 += __shfl_xor(v2, m); v3 += __shfl_xor(v3, m);
    }
    if ((t & 63) == 0) {
      int wv = t >> 6;
      red[wv][0]=v0; red[wv][1]=v1; red[wv][2]=v2; red[wv][3]=v3;
    }
    __syncthreads();
    if (t == 0) {
      float* dst = h ? g_pd4 : g_pu4;
      #pragma unroll
      for (int c = 0; c < 4; ++c)
        dst[j*4 + c] = (red[0][c]+red[1][c]+red[2][c]+red[3][c]) * (1.f/256.f);
    }
    __syncthreads();
  }
}

// ---------------- p-channel update. MODE 0: from geometry; 1: load+store; 2: load only ----
template<int MODE>
__global__ __launch_bounds__(256) void k_pup(const float* __restrict__ W,
                                             const float* __restrict__ Wb,
                                             const float* __restrict__ r,
                                             int src, int dst) {
  __shared__ __align__(16) float psh[4][64];
  int t = threadIdx.x, lane = t & 63, wv = t >> 6;
  int gw = blockIdx.x*4 + wv;          // 0..4095
  int j = gw >> 3, chunk = gw & 7;
  int i0 = chunk * 64;
  float macc = 0.f;
  if (MODE == 0) {
    float w0 = W[lane], w1 = W[64+lane], w2 = W[128+lane], w3 = W[192+lane];
    float bb = Wb[lane];
    float rjx = r[3*j], rjy = r[3*j+1], rjz = r[3*j+2];
    float* pout = g_p[0];
    for (int ii = 0; ii < 64; ++ii) {
      int i = i0 + ii;
      float dx = rjx - r[3*i], dy = rjy - r[3*i+1], dz = rjz - r[3*i+2];
      float ee = (i == j) ? 1.f : 0.f;
      float ex = dx+ee, ey = dy+ee, ez = dz+ee;
      float len = sqrtf(ex*ex + ey*ey + ez*ez);
      float y = tanh_fast(bb + dx*w0 + dy*w1 + dz*w2 + len*w3);
      pout[(i*NE + j)*64 + lane] = y;
      macc += y;
    }
  } else {
    const float* pin = g_p[src];
    float* pout = g_p[dst];
    float wcol[64];
    #pragma unroll
    for (int k = 0; k < 64; ++k) wcol[k] = W[k*64 + lane];
    float bb = Wb[lane];
    for (int ii = 0; ii < 64; ++ii) {
      int i = i0 + ii;
      int base = (i*NE + j)*64;
      float x = pin[base + lane];
      psh[wv][lane] = x;
      float acc = bb;
      #pragma unroll
      for (int g = 0; g < 16; ++g) {
        float4 pv = *(const float4*)&psh[wv][4*g];   // wave-uniform broadcast reads
        acc += pv.x*wcol[4*g] + pv.y*wcol[4*g+1] + pv.z*wcol[4*g+2] + pv.w*wcol[4*g+3];
      }
      float y = tanh_fast(acc) + x;                  // residual (layers >= 1)
      if (MODE == 1) pout[base + lane] = y;
      macc += y;
    }
  }
  g_part[chunk*(NE*64) + j*64 + lane] = macc;
}

// ---------------- finalize p-means + s-means ----------------
__global__ __launch_bounds__(256) void k_reduce(int svsel) {
  int bid = blockIdx.x, t = threadIdx.x;
  if (bid < 256) {
    int idx = bid*256 + t;
    int half = idx >> 15, rem = idx & 32767;
    int j = rem >> 6, l = rem & 63;
    const float* pp = g_part + half*(4*NE*64);
    float s = pp[0*(NE*64)+j*64+l] + pp[1*(NE*64)+j*64+l]
            + pp[2*(NE*64)+j*64+l] + pp[3*(NE*64)+j*64+l];
    (half ? g_pd : g_pu)[j*64 + l] = s * (1.f/256.f);
  } else {
    int h = bid - 256;
    const float* sv = g_sv[svsel];
    float s = 0.f;
    for (int i = 0; i < 256; ++i) s += sv[(h*256 + i)*256 + t];
    (h ? g_sd : g_su)[t] = s * (1.f/256.f);
  }
}

// ---------------- generic s-channel matmul (layers / heads / orbitals) ----------------
// which: 0=layer0, 1..3=layer l, 4=head_u, 5=head_d, 6=orb_u, 7=orb_d
template<int PUK, int SVK, int MEANK>
__global__ __launch_bounds__(256) void k_smm(int which, const float* __restrict__ W,
                                             const float* __restrict__ Wb) {
  constexpr int MAINK = 2*PUK + SVK;
  __shared__ __align__(16) float wsl[MAINK*32];
  __shared__ float insl[32*(MAINK+1)];
  __shared__ float biasv[32];
  __shared__ float bred[256];
  const float *pu_p=nullptr, *pd_p=nullptr, *sv_p=nullptr, *su_p=nullptr, *sd_p=nullptr;
  const float *res_p=nullptr, *rs_p=nullptr;
  float* out_p = nullptr;
  int row0 = 0, dotanh = 1;
  switch (which) {
    case 0: pu_p=g_pu4; pd_p=g_pd4; su_p=g_su0; sd_p=g_sd0; sv_p=g_sv0; out_p=g_sv[0]; break;
    case 1: case 2: case 3:
      pu_p=g_pu; pd_p=g_pd; su_p=g_su; sd_p=g_sd;
      sv_p=g_sv[(which+1)&1]; res_p=sv_p; out_p=g_sv[which&1]; break;
    case 4: pu_p=g_pu; pd_p=g_pd; su_p=g_su; sd_p=g_sd; sv_p=g_sv[1]; out_p=g_hu; break;
    case 5: pu_p=g_pu; pd_p=g_pd; su_p=g_su; sd_p=g_sd; sv_p=g_sv[1]; out_p=g_hd; row0=256; break;
    case 6: sv_p=g_hu; out_p=g_orbu; rs_p=g_f;       dotanh=0; break;
    default: sv_p=g_hd; out_p=g_orbd; rs_p=g_f+256;  dotanh=0; break;
  }
  int t = threadIdx.x;
  int rg = blockIdx.x, cg = blockIdx.y;
  int col0 = cg * 32;
  for (int idx = t; idx < MAINK*32; idx += 256) {
    int c = idx >> 5, cl = idx & 31;
    wsl[idx] = W[(2*MEANK + c)*256 + col0 + cl];
  }
  for (int rr = 0; rr < 32; ++rr) {
    int row = row0 + rg*32 + rr;
    for (int c = t; c < MAINK; c += 256) {
      float v;
      if (c < PUK) v = pu_p[row*PUK + c];
      else if (c < 2*PUK) v = pd_p[row*PUK + (c - PUK)];
      else v = sv_p[row*SVK + (c - 2*PUK)];
      insl[rr*(MAINK+1) + c] = v;
    }
  }
  {
    int pcol = t & 31, ps = t >> 5;
    float bacc = 0.f;
    if (MEANK > 0) {
      for (int c = ps; c < MEANK; c += 8)
        bacc += su_p[c]*W[c*256 + col0 + pcol] + sd_p[c]*W[(MEANK + c)*256 + col0 + pcol];
    }
    bred[ps*32 + pcol] = bacc;
  }
  __syncthreads();
  if (t < 32) {
    float s = Wb[col0 + t];
    #pragma unroll
    for (int p8 = 0; p8 < 8; ++p8) s += bred[p8*32 + t];
    biasv[t] = s;
  }
  __syncthreads();
  int c4 = t & 7, rl = t >> 3;
  float a0 = biasv[4*c4], a1 = biasv[4*c4+1], a2 = biasv[4*c4+2], a3 = biasv[4*c4+3];
  const float* inrow = &insl[rl*(MAINK+1)];
  for (int c = 0; c < MAINK; ++c) {
    float iv = inrow[c];
    float4 wv = *(const float4*)&wsl[c*32 + 4*c4];
    a0 += iv*wv.x; a1 += iv*wv.y; a2 += iv*wv.z; a3 += iv*wv.w;
  }
  int rowA = rg*32 + rl;
  int col = col0 + 4*c4;
  if (dotanh) { a0=tanh_fast(a0); a1=tanh_fast(a1); a2=tanh_fast(a2); a3=tanh_fast(a3); }
  if (res_p) {
    float4 rv = *(const float4*)&res_p[rowA*256 + col];
    a0 += rv.x; a1 += rv.y; a2 += rv.z; a3 += rv.w;
  }
  if (rs_p) { float fsc = rs_p[rowA]; a0*=fsc; a1*=fsc; a2*=fsc; a3*=fsc; }
  float4 ov; ov.x=a0; ov.y=a1; ov.z=a2; ov.w=a3;
  *(float4*)&out_p[rowA*256 + col] = ov;
}

// ---------------- register-resident LU with implicit partial pivoting ----------------
// __launch_bounds__(512, 2): 8 waves/block over 4 SIMDs = 2 waves/SIMD -> 256-VGPR
// budget so av[32] (128 VGPRs) stays in registers (R1 had VGPR=84 + 268MB scratch spill).
__global__ __launch_bounds__(512, 2) void k_lu() {
  __shared__ __align__(16) float colbuf[256];
  __shared__ __align__(16) float prow[2][256];       // double-buffered pivot row
  const float* A = (blockIdx.x == 0) ? g_orbu : g_orbd;
  int t = threadIdx.x;
  int q = t >> 8;            // column half: [128q, 128q+127]
  int r = t & 255;           // owned row
  int lane = t & 63;
  float4 av[32];
  const float4* Ar = (const float4*)(A + r*256 + q*128);
  #pragma unroll
  for (int g = 0; g < 32; ++g) av[g] = Ar[g];
  unsigned um = 0;           // 4-bit used mask for candidate rows 4*lane..4*lane+3
  if (q == 0) colbuf[r] = av[0].x;
  __syncthreads();
  float logsum = 0.f;
  float multv;
  // initial pivot search (column 0)
  {
    float4 cv = *(const float4*)&colbuf[4*lane];
    float cr = colbuf[r];
    unsigned b0 = (__float_as_uint(fabsf(cv.x)) & 0xFFFFFF00u) | (unsigned)(4*lane+0);
    unsigned b1 = (__float_as_uint(fabsf(cv.y)) & 0xFFFFFF00u) | (unsigned)(4*lane+1);
    unsigned b2 = (__float_as_uint(fabsf(cv.z)) & 0xFFFFFF00u) | (unsigned)(4*lane+2);
    unsigned b3 = (__float_as_uint(fabsf(cv.w)) & 0xFFFFFF00u) | (unsigned)(4*lane+3);
    unsigned bb = max(max(b0,b1), max(b2,b3));
    #pragma unroll
    for (int m = 1; m < 64; m <<= 1) {
      unsigned ob = __shfl_xor(bb, m);
      bb = ob > bb ? ob : bb;
    }
    int p = (int)(bb & 255u);
    float piv = colbuf[p];
    logsum += logf(fabsf(piv));
    multv = cr / piv;
    if ((p >> 2) == lane) um |= 1u << (p & 3);
    if (r == p) {
      #pragma unroll
      for (int g = 0; g < 32; ++g) *(float4*)&prow[0][q*128 + 4*g] = av[g];
    }
    __syncthreads();
  }
  for (int k = 0; k < 255; ++k) {
    int buf = k & 1;
    int kn = k + 1;
    // phase 1: owners of column k+1 publish its post-update-k value
    if ((kn >> 7) == q) {
      int kl = kn & 127, gsel = kl >> 2, cc = kl & 3;
      float4 s = av[0];
      #pragma unroll
      for (int g = 1; g < 32; ++g) if (g == gsel) s = av[g];
      float elem = (cc==0) ? s.x : (cc==1) ? s.y : (cc==2) ? s.z : s.w;
      colbuf[r] = elem - multv * prow[buf][kn];
    }
    __syncthreads();
    // phase 2: pivot search for column k+1 interleaved with bulk rank-1 update k
    float4 cv = *(const float4*)&colbuf[4*lane];
    float cr = colbuf[r];
    #pragma unroll
    for (int g = 0; g < 32; ++g) {
      float4 pr = *(const float4*)&prow[buf][q*128 + 4*g];
      av[g].x -= multv*pr.x; av[g].y -= multv*pr.y;
      av[g].z -= multv*pr.z; av[g].w -= multv*pr.w;
    }
    unsigned b0 = (um & 1u) ? 0u : ((__float_as_uint(fabsf(cv.x)) & 0xFFFFFF00u) | (unsigned)(4*lane+0));
    unsigned b1 = (um & 2u) ? 0u : ((__float_as_uint(fabsf(cv.y)) & 0xFFFFFF00u) | (unsigned)(4*lane+1));
    unsigned b2 = (um & 4u) ? 0u : ((__float_as_uint(fabsf(cv.z)) & 0xFFFFFF00u) | (unsigned)(4*lane+2));
    unsigned b3 = (um & 8u) ? 0u : ((__float_as_uint(fabsf(cv.w)) & 0xFFFFFF00u) | (unsigned)(4*lane+3));
    unsigned bb = max(max(b0,b1), max(b2,b3));
    #pragma unroll
    for (int m = 1; m < 64; m <<= 1) {
      unsigned ob = __shfl_xor(bb, m);
      bb = ob > bb ? ob : bb;
    }
    int p = (int)(bb & 255u);
    float piv = colbuf[p];
    logsum += logf(fabsf(piv));
    float mnext = cr / piv;
    if ((p >> 2) == lane) um |= 1u << (p & 3);
    if (r == p) {
      #pragma unroll
      for (int g = 0; g < 32; ++g) *(float4*)&prow[buf^1][q*128 + 4*g] = av[g];
    }
    __syncthreads();
    multv = mnext;
  }
  if (t == 0) g_logs[blockIdx.x] = logsum;
}

__global__ void k_final(float* out) { out[0] = g_logs[0] + g_logs[1]; }

// ---------------- launch ----------------
extern "C" void kernel_launch(void* const* d_in, const int* in_sizes, int n_in,
                              void* d_out, int out_size, void* d_ws, size_t ws_size,
                              hipStream_t stream) {
  const float* r     = (const float*)d_in[0];
  const float* a     = (const float*)d_in[1];
  const float* V0_W  = (const float*)d_in[2];
  const float* V0_b  = (const float*)d_in[3];
  const float* Vr_W  = (const float*)d_in[4];
  const float* Vr_b  = (const float*)d_in[5];
  const float* W0_W  = (const float*)d_in[6];
  const float* W0_b  = (const float*)d_in[7];
  const float* Wr_W  = (const float*)d_in[8];
  const float* Wr_b  = (const float*)d_in[9];
  const float* Vhu_W = (const float*)d_in[10];
  const float* Vhu_b = (const float*)d_in[11];
  const float* Vhd_W = (const float*)d_in[12];
  const float* Vhd_b = (const float*)d_in[13];
  const float* wu_W  = (const float*)d_in[14];
  const float* wu_b  = (const float*)d_in[15];
  const float* wd_W  = (const float*)d_in[16];
  const float* wd_b  = (const float*)d_in[17];
  float* out = (float*)d_out;

  k_geom<<<1, 512, 0, stream>>>(r, a);
  k_pmean0<<<512, 256, 0, stream>>>(r);

  // layer 0
  k_smm<4,64,64><<<dim3(16,8), 256, 0, stream>>>(0, V0_W, V0_b);
  k_pup<0><<<1024, 256, 0, stream>>>(W0_W, W0_b, r, 0, 0);
  k_reduce<<<258, 256, 0, stream>>>(0);
  // layer 1
  k_smm<64,256,256><<<dim3(16,8), 256, 0, stream>>>(1, Vr_W + 0*896*256, Vr_b + 0);
  k_pup<1><<<1024, 256, 0, stream>>>(Wr_W + 0*4096, Wr_b + 0, r, 0, 1);
  k_reduce<<<258, 256, 0, stream>>>(1);
  // layer 2
  k_smm<64,256,256><<<dim3(16,8), 256, 0, stream>>>(2, Vr_W + 1*896*256, Vr_b + 256);
  k_pup<1><<<1024, 256, 0, stream>>>(Wr_W + 1*4096, Wr_b + 64, r, 1, 0);
  k_reduce<<<258, 256, 0, stream>>>(0);
  // layer 3 (p4 not stored; only its means)
  k_smm<64,256,256><<<dim3(16,8), 256, 0, stream>>>(3, Vr_W + 2*896*256, Vr_b + 512);
  k_pup<2><<<1024, 256, 0, stream>>>(Wr_W + 2*4096, Wr_b + 128, r, 0, 0);
  k_reduce<<<258, 256, 0, stream>>>(1);
  // heads
  k_smm<64,256,256><<<dim3(8,8), 256, 0, stream>>>(4, Vhu_W, Vhu_b);
  k_smm<64,256,256><<<dim3(8,8), 256, 0, stream>>>(5, Vhd_W, Vhd_b);
  // orbitals
  k_smm<0,256,0><<<dim3(8,8), 256, 0, stream>>>(6, wu_W, wu_b);
  k_smm<0,256,0><<<dim3(8,8), 256, 0, stream>>>(7, wd_W, wd_b);
  // log|det| x2 and combine
  k_lu<<<2, 512, 0, stream>>>();
  k_final<<<1, 1, 0, stream>>>(out);
}

// Round 3
// 992.508 us; speedup vs baseline: 1.0643x; 1.0218x over previous
//
#include <hip/hip_runtime.h>
#include <hip/hip_bf16.h>

#define NE 512

// ---------------- static device buffers (avoid d_ws dependence) ----------------
__device__ __align__(16) float g_p[2][NE*NE*64];     // ping-pong pair features (67MB each)
__device__ __align__(16) float g_sv0[NE*64];
__device__ __align__(16) float g_sv[2][NE*256];
__device__ __align__(16) float g_pu4[NE*4];
__device__ __align__(16) float g_pd4[NE*4];
__device__ __align__(16) float g_pu[NE*64];
__device__ __align__(16) float g_pd[NE*64];
__device__ __align__(16) float g_su0[64];
__device__ __align__(16) float g_sd0[64];
__device__ __align__(16) float g_su[256];
__device__ __align__(16) float g_sd[256];
__device__ __align__(16) float g_part[8*NE*64];      // per-(j,chunk) partial means of p
__device__ __align__(16) float g_f[NE];              // sum_a exp(-|r_i - a|)
__device__ __align__(16) float g_hu[256*256];
__device__ __align__(16) float g_hd[256*256];
__device__ __align__(16) float g_orbu[256*256];
__device__ __align__(16) float g_orbd[256*256];
__device__ float g_logs[2];

__device__ __forceinline__ float tanh_fast(float x) {
  float e = __expf(2.f * x);
  return 1.f - 2.f / (e + 1.f);
}

// ---------------- K0: geometry -> s_v0, f, su0/sd0 ----------------
__global__ __launch_bounds__(512) void k_geom(const float* __restrict__ r,
                                              const float* __restrict__ a) {
  int e = threadIdx.x;
  float rx = r[3*e], ry = r[3*e+1], rz = r[3*e+2];
  float facc = 0.f;
  #pragma unroll
  for (int at = 0; at < 16; ++at) {
    float dx = rx - a[3*at], dy = ry - a[3*at+1], dz = rz - a[3*at+2];
    float len = sqrtf(dx*dx + dy*dy + dz*dz);
    g_sv0[e*64 + 4*at + 0] = dx;
    g_sv0[e*64 + 4*at + 1] = dy;
    g_sv0[e*64 + 4*at + 2] = dz;
    g_sv0[e*64 + 4*at + 3] = len;
    facc += expf(-len);
  }
  g_f[e] = facc;
  __syncthreads();            // global writes visible within block after barrier
  if (e < 128) {
    int h = e >> 6, c = e & 63;
    float s = 0.f;
    for (int i = 0; i < 256; ++i) s += g_sv0[(h*256 + i)*64 + c];
    (h ? g_sd0 : g_su0)[c] = s * (1.f/256.f);
  }
}

// ---------------- K0b: means of p0 (4-dim geometry pairs) ----------------
__global__ __launch_bounds__(256) void k_pmean0(const float* __restrict__ r) {
  int j = blockIdx.x, t = threadIdx.x;
  float rjx = r[3*j], rjy = r[3*j+1], rjz = r[3*j+2];
  __shared__ float red[4][4];
  for (int h = 0; h < 2; ++h) {
    int i = h*256 + t;
    float dx = rjx - r[3*i], dy = rjy - r[3*i+1], dz = rjz - r[3*i+2];
    float ee = (i == j) ? 1.f : 0.f;
    float ex = dx+ee, ey = dy+ee, ez = dz+ee;
    float len = sqrtf(ex*ex + ey*ey + ez*ez);
    float v0 = dx, v1 = dy, v2 = dz, v3 = len;
    #pragma unroll
    for (int m = 1; m < 64; m <<= 1) {
      v0 += __shfl_xor(v0, m); v1 += __shfl_xor(v1, m);
      v2 += __shfl_xor(v2, m); v3 += __shfl_xor(v3, m);
    }
    if ((t & 63) == 0) {
      int wv = t >> 6;
      red[wv][0]=v0; red[wv][1]=v1; red[wv][2]=v2; red[wv][3]=v3;
    }
    __syncthreads();
    if (t == 0) {
      float* dst = h ? g_pd4 : g_pu4;
      #pragma unroll
      for (int c = 0; c < 4; ++c)
        dst[j*4 + c] = (red[0][c]+red[1][c]+red[2][c]+red[3][c]) * (1.f/256.f);
    }
    __syncthreads();
  }
}

// ---------------- p-channel update. MODE 0: from geometry; 1: load+store; 2: load only ----
template<int MODE>
__global__ __launch_bounds__(256) void k_pup(const float* __restrict__ W,
                                             const float* __restrict__ Wb,
                                             const float* __restrict__ r,
                                             int src, int dst) {
  __shared__ __align__(16) float psh[4][64];
  int t = threadIdx.x, lane = t & 63, wv = t >> 6;
  int gw = blockIdx.x*4 + wv;          // 0..4095
  int j = gw >> 3, chunk = gw & 7;
  int i0 = chunk * 64;
  float macc = 0.f;
  if (MODE == 0) {
    float w0 = W[lane], w1 = W[64+lane], w2 = W[128+lane], w3 = W[192+lane];
    float bb = Wb[lane];
    float rjx = r[3*j], rjy = r[3*j+1], rjz = r[3*j+2];
    float* pout = g_p[0];
    for (int ii = 0; ii < 64; ++ii) {
      int i = i0 + ii;
      float dx = rjx - r[3*i], dy = rjy - r[3*i+1], dz = rjz - r[3*i+2];
      float ee = (i == j) ? 1.f : 0.f;
      float ex = dx+ee, ey = dy+ee, ez = dz+ee;
      float len = sqrtf(ex*ex + ey*ey + ez*ez);
      float y = tanh_fast(bb + dx*w0 + dy*w1 + dz*w2 + len*w3);
      pout[(i*NE + j)*64 + lane] = y;
      macc += y;
    }
  } else {
    const float* pin = g_p[src];
    float* pout = g_p[dst];
    float wcol[64];
    #pragma unroll
    for (int k = 0; k < 64; ++k) wcol[k] = W[k*64 + lane];
    float bb = Wb[lane];
    for (int ii = 0; ii < 64; ++ii) {
      int i = i0 + ii;
      int base = (i*NE + j)*64;
      float x = pin[base + lane];
      psh[wv][lane] = x;
      float acc = bb;
      #pragma unroll
      for (int g = 0; g < 16; ++g) {
        float4 pv = *(const float4*)&psh[wv][4*g];   // wave-uniform broadcast reads
        acc += pv.x*wcol[4*g] + pv.y*wcol[4*g+1] + pv.z*wcol[4*g+2] + pv.w*wcol[4*g+3];
      }
      float y = tanh_fast(acc) + x;                  // residual (layers >= 1)
      if (MODE == 1) pout[base + lane] = y;
      macc += y;
    }
  }
  g_part[chunk*(NE*64) + j*64 + lane] = macc;
}

// ---------------- finalize p-means + s-means ----------------
__global__ __launch_bounds__(256) void k_reduce(int svsel) {
  int bid = blockIdx.x, t = threadIdx.x;
  if (bid < 256) {
    int idx = bid*256 + t;
    int half = idx >> 15, rem = idx & 32767;
    int j = rem >> 6, l = rem & 63;
    const float* pp = g_part + half*(4*NE*64);
    float s = pp[0*(NE*64)+j*64+l] + pp[1*(NE*64)+j*64+l]
            + pp[2*(NE*64)+j*64+l] + pp[3*(NE*64)+j*64+l];
    (half ? g_pd : g_pu)[j*64 + l] = s * (1.f/256.f);
  } else {
    int h = bid - 256;
    const float* sv = g_sv[svsel];
    float s = 0.f;
    for (int i = 0; i < 256; ++i) s += sv[(h*256 + i)*256 + t];
    (h ? g_sd : g_su)[t] = s * (1.f/256.f);
  }
}

// ---------------- generic s-channel matmul (layers / heads / orbitals) ----------------
// which: 0=layer0, 1..3=layer l, 4=head_u, 5=head_d, 6=orb_u, 7=orb_d
template<int PUK, int SVK, int MEANK>
__global__ __launch_bounds__(256) void k_smm(int which, const float* __restrict__ W,
                                             const float* __restrict__ Wb) {
  constexpr int MAINK = 2*PUK + SVK;
  __shared__ __align__(16) float wsl[MAINK*32];
  __shared__ float insl[32*(MAINK+1)];
  __shared__ float biasv[32];
  __shared__ float bred[256];
  const float *pu_p=nullptr, *pd_p=nullptr, *sv_p=nullptr, *su_p=nullptr, *sd_p=nullptr;
  const float *res_p=nullptr, *rs_p=nullptr;
  float* out_p = nullptr;
  int row0 = 0, dotanh = 1;
  switch (which) {
    case 0: pu_p=g_pu4; pd_p=g_pd4; su_p=g_su0; sd_p=g_sd0; sv_p=g_sv0; out_p=g_sv[0]; break;
    case 1: case 2: case 3:
      pu_p=g_pu; pd_p=g_pd; su_p=g_su; sd_p=g_sd;
      sv_p=g_sv[(which+1)&1]; res_p=sv_p; out_p=g_sv[which&1]; break;
    case 4: pu_p=g_pu; pd_p=g_pd; su_p=g_su; sd_p=g_sd; sv_p=g_sv[1]; out_p=g_hu; break;
    case 5: pu_p=g_pu; pd_p=g_pd; su_p=g_su; sd_p=g_sd; sv_p=g_sv[1]; out_p=g_hd; row0=256; break;
    case 6: sv_p=g_hu; out_p=g_orbu; rs_p=g_f;       dotanh=0; break;
    default: sv_p=g_hd; out_p=g_orbd; rs_p=g_f+256;  dotanh=0; break;
  }
  int t = threadIdx.x;
  int rg = blockIdx.x, cg = blockIdx.y;
  int col0 = cg * 32;
  for (int idx = t; idx < MAINK*32; idx += 256) {
    int c = idx >> 5, cl = idx & 31;
    wsl[idx] = W[(2*MEANK + c)*256 + col0 + cl];
  }
  for (int rr = 0; rr < 32; ++rr) {
    int row = row0 + rg*32 + rr;
    for (int c = t; c < MAINK; c += 256) {
      float v;
      if (c < PUK) v = pu_p[row*PUK + c];
      else if (c < 2*PUK) v = pd_p[row*PUK + (c - PUK)];
      else v = sv_p[row*SVK + (c - 2*PUK)];
      insl[rr*(MAINK+1) + c] = v;
    }
  }
  {
    int pcol = t & 31, ps = t >> 5;
    float bacc = 0.f;
    if (MEANK > 0) {
      for (int c = ps; c < MEANK; c += 8)
        bacc += su_p[c]*W[c*256 + col0 + pcol] + sd_p[c]*W[(MEANK + c)*256 + col0 + pcol];
    }
    bred[ps*32 + pcol] = bacc;
  }
  __syncthreads();
  if (t < 32) {
    float s = Wb[col0 + t];
    #pragma unroll
    for (int p8 = 0; p8 < 8; ++p8) s += bred[p8*32 + t];
    biasv[t] = s;
  }
  __syncthreads();
  int c4 = t & 7, rl = t >> 3;
  float a0 = biasv[4*c4], a1 = biasv[4*c4+1], a2 = biasv[4*c4+2], a3 = biasv[4*c4+3];
  const float* inrow = &insl[rl*(MAINK+1)];
  for (int c = 0; c < MAINK; ++c) {
    float iv = inrow[c];
    float4 wv = *(const float4*)&wsl[c*32 + 4*c4];
    a0 += iv*wv.x; a1 += iv*wv.y; a2 += iv*wv.z; a3 += iv*wv.w;
  }
  int rowA = rg*32 + rl;
  int col = col0 + 4*c4;
  if (dotanh) { a0=tanh_fast(a0); a1=tanh_fast(a1); a2=tanh_fast(a2); a3=tanh_fast(a3); }
  if (res_p) {
    float4 rv = *(const float4*)&res_p[rowA*256 + col];
    a0 += rv.x; a1 += rv.y; a2 += rv.z; a3 += rv.w;
  }
  if (rs_p) { float fsc = rs_p[rowA]; a0*=fsc; a1*=fsc; a2*=fsc; a3*=fsc; }
  float4 ov; ov.x=a0; ov.y=a1; ov.z=a2; ov.w=a3;
  *(float4*)&out_p[rowA*256 + col] = ov;
}

// ---------------- register-resident LU with implicit partial pivoting ----------------
// R2 lesson (rule #20): float4 av[32] + variable-index extract => compiler alloca'd the
// whole matrix into scratch (VGPR=84, 267MB scratch traffic). v3: 16 NAMED float4
// variables, macro-expanded; column extract is a uniform switch (gsel/cc derive from
// the loop counter, so it's a scalar branch). 1024 threads = 4 column-quarters.
#define REP16(M) M(0) M(1) M(2) M(3) M(4) M(5) M(6) M(7) M(8) M(9) M(10) M(11) M(12) M(13) M(14) M(15)

__global__ __launch_bounds__(1024, 4) void k_lu() {
  __shared__ __align__(16) float colbuf[256];
  __shared__ __align__(16) float prow[2][256];       // double-buffered pivot row
  const float* A = (blockIdx.x == 0) ? g_orbu : g_orbd;
  int t = threadIdx.x;
  int q = t >> 8;            // column quarter: [64q, 64q+63]
  int r = t & 255;           // owned row
  int lane = t & 63;
  const float4* Ar = (const float4*)(A + r*256 + q*64);
#define LOADG(G) float4 A##G = Ar[G];
  REP16(LOADG)
#undef LOADG
  unsigned um = 0;           // used-mask for candidate rows 4*lane..4*lane+3
  if (q == 0) colbuf[r] = A0.x;
  __syncthreads();
  float logsum = 0.f;
  float multv;
  // initial pivot search (column 0)
  {
    float4 cv = *(const float4*)&colbuf[4*lane];
    float cr = colbuf[r];
    unsigned b0 = (__float_as_uint(fabsf(cv.x)) & 0xFFFFFF00u) | (unsigned)(4*lane+0);
    unsigned b1 = (__float_as_uint(fabsf(cv.y)) & 0xFFFFFF00u) | (unsigned)(4*lane+1);
    unsigned b2 = (__float_as_uint(fabsf(cv.z)) & 0xFFFFFF00u) | (unsigned)(4*lane+2);
    unsigned b3 = (__float_as_uint(fabsf(cv.w)) & 0xFFFFFF00u) | (unsigned)(4*lane+3);
    unsigned bb = max(max(b0,b1), max(b2,b3));
    #pragma unroll
    for (int m = 1; m < 64; m <<= 1) {
      unsigned ob = __shfl_xor(bb, m);
      bb = ob > bb ? ob : bb;
    }
    int p = (int)(bb & 255u);
    float piv = colbuf[p];
    logsum += logf(fabsf(piv));
    multv = cr / piv;
    if ((p >> 2) == lane) um |= 1u << (p & 3);
    if (r == p) {
#define STG(G) *(float4*)&prow[0][q*64 + 4*G] = A##G;
      REP16(STG)
#undef STG
    }
    __syncthreads();
  }
  for (int k = 0; k < 255; ++k) {
    int buf = k & 1;
    int kn = k + 1;
    // phase 1: owner quarter publishes column k+1 (applying pending update k on the fly)
    if ((kn >> 6) == q) {
      int gsel = (kn & 63) >> 2, cc = kn & 3;
      float4 v4;
      switch (gsel) {
#define CASEG(G) case G: v4 = A##G; break;
        REP16(CASEG)
#undef CASEG
        default: v4 = A0; break;
      }
      float elem = (cc==0) ? v4.x : (cc==1) ? v4.y : (cc==2) ? v4.z : v4.w;
      colbuf[r] = elem - multv * prow[buf][kn];
    }
    __syncthreads();
    // phase 2: pivot search for column k+1 interleaved with bulk rank-1 update k
    float4 cv = *(const float4*)&colbuf[4*lane];
    float cr = colbuf[r];
    bool alive = (q*64 + 63) > k;
    if (alive) {
#define UPDG(G) { float4 pr = *(const float4*)&prow[buf][q*64 + 4*G]; \
                  A##G.x -= multv*pr.x; A##G.y -= multv*pr.y; \
                  A##G.z -= multv*pr.z; A##G.w -= multv*pr.w; }
      REP16(UPDG)
#undef UPDG
    }
    unsigned b0 = (um & 1u) ? 0u : ((__float_as_uint(fabsf(cv.x)) & 0xFFFFFF00u) | (unsigned)(4*lane+0));
    unsigned b1 = (um & 2u) ? 0u : ((__float_as_uint(fabsf(cv.y)) & 0xFFFFFF00u) | (unsigned)(4*lane+1));
    unsigned b2 = (um & 4u) ? 0u : ((__float_as_uint(fabsf(cv.z)) & 0xFFFFFF00u) | (unsigned)(4*lane+2));
    unsigned b3 = (um & 8u) ? 0u : ((__float_as_uint(fabsf(cv.w)) & 0xFFFFFF00u) | (unsigned)(4*lane+3));
    unsigned bb = max(max(b0,b1), max(b2,b3));
    #pragma unroll
    for (int m = 1; m < 64; m <<= 1) {
      unsigned ob = __shfl_xor(bb, m);
      bb = ob > bb ? ob : bb;
    }
    int p = (int)(bb & 255u);
    float piv = colbuf[p];
    logsum += logf(fabsf(piv));
    float mnext = cr / piv;
    if ((p >> 2) == lane) um |= 1u << (p & 3);
    if (r == p) {
#define STG(G) *(float4*)&prow[buf^1][q*64 + 4*G] = A##G;
      REP16(STG)
#undef STG
    }
    __syncthreads();
    multv = mnext;
  }
  if (t == 0) g_logs[blockIdx.x] = logsum;
}

__global__ void k_final(float* out) { out[0] = g_logs[0] + g_logs[1]; }

// ---------------- launch ----------------
extern "C" void kernel_launch(void* const* d_in, const int* in_sizes, int n_in,
                              void* d_out, int out_size, void* d_ws, size_t ws_size,
                              hipStream_t stream) {
  const float* r     = (const float*)d_in[0];
  const float* a     = (const float*)d_in[1];
  const float* V0_W  = (const float*)d_in[2];
  const float* V0_b  = (const float*)d_in[3];
  const float* Vr_W  = (const float*)d_in[4];
  const float* Vr_b  = (const float*)d_in[5];
  const float* W0_W  = (const float*)d_in[6];
  const float* W0_b  = (const float*)d_in[7];
  const float* Wr_W  = (const float*)d_in[8];
  const float* Wr_b  = (const float*)d_in[9];
  const float* Vhu_W = (const float*)d_in[10];
  const float* Vhu_b = (const float*)d_in[11];
  const float* Vhd_W = (const float*)d_in[12];
  const float* Vhd_b = (const float*)d_in[13];
  const float* wu_W  = (const float*)d_in[14];
  const float* wu_b  = (const float*)d_in[15];
  const float* wd_W  = (const float*)d_in[16];
  const float* wd_b  = (const float*)d_in[17];
  float* out = (float*)d_out;

  k_geom<<<1, 512, 0, stream>>>(r, a);
  k_pmean0<<<512, 256, 0, stream>>>(r);

  // layer 0
  k_smm<4,64,64><<<dim3(16,8), 256, 0, stream>>>(0, V0_W, V0_b);
  k_pup<0><<<1024, 256, 0, stream>>>(W0_W, W0_b, r, 0, 0);
  k_reduce<<<258, 256, 0, stream>>>(0);
  // layer 1
  k_smm<64,256,256><<<dim3(16,8), 256, 0, stream>>>(1, Vr_W + 0*896*256, Vr_b + 0);
  k_pup<1><<<1024, 256, 0, stream>>>(Wr_W + 0*4096, Wr_b + 0, r, 0, 1);
  k_reduce<<<258, 256, 0, stream>>>(1);
  // layer 2
  k_smm<64,256,256><<<dim3(16,8), 256, 0, stream>>>(2, Vr_W + 1*896*256, Vr_b + 256);
  k_pup<1><<<1024, 256, 0, stream>>>(Wr_W + 1*4096, Wr_b + 64, r, 1, 0);
  k_reduce<<<258, 256, 0, stream>>>(0);
  // layer 3 (p4 not stored; only its means)
  k_smm<64,256,256><<<dim3(16,8), 256, 0, stream>>>(3, Vr_W + 2*896*256, Vr_b + 512);
  k_pup<2><<<1024, 256, 0, stream>>>(Wr_W + 2*4096, Wr_b + 128, r, 0, 0);
  k_reduce<<<258, 256, 0, stream>>>(1);
  // heads
  k_smm<64,256,256><<<dim3(8,8), 256, 0, stream>>>(4, Vhu_W, Vhu_b);
  k_smm<64,256,256><<<dim3(8,8), 256, 0, stream>>>(5, Vhd_W, Vhd_b);
  // orbitals
  k_smm<0,256,0><<<dim3(8,8), 256, 0, stream>>>(6, wu_W, wu_b);
  k_smm<0,256,0><<<dim3(8,8), 256, 0, stream>>>(7, wd_W, wd_b);
  // log|det| x2 and combine
  k_lu<<<2, 1024, 0, stream>>>();
  k_final<<<1, 1, 0, stream>>>(out);
}

// Round 4
// 802.248 us; speedup vs baseline: 1.3167x; 1.2372x over previous
//
#include <hip/hip_runtime.h>
#include <hip/hip_bf16.h>

#define NE 512

// ---------------- static device buffers (avoid d_ws dependence) ----------------
__device__ __align__(16) float g_p[2][NE*NE*64];     // ping-pong pair features (67MB each)
__device__ __align__(16) float g_sv0[NE*64];
__device__ __align__(16) float g_sv[2][NE*256];
__device__ __align__(16) float g_pu4[NE*4];
__device__ __align__(16) float g_pd4[NE*4];
__device__ __align__(16) float g_pu[NE*64];
__device__ __align__(16) float g_pd[NE*64];
__device__ __align__(16) float g_su0[64];
__device__ __align__(16) float g_sd0[64];
__device__ __align__(16) float g_su[256];
__device__ __align__(16) float g_sd[256];
__device__ __align__(16) float g_part[8*NE*64];      // per-(j,chunk) partial means of p
__device__ __align__(16) float g_f[NE];              // sum_a exp(-|r_i - a|)
__device__ __align__(16) float g_hu[256*256];
__device__ __align__(16) float g_hd[256*256];
__device__ __align__(16) float g_orbu[256*256];
__device__ __align__(16) float g_orbd[256*256];
__device__ float g_logs[2];

__device__ __forceinline__ float tanh_fast(float x) {
  float e = __expf(2.f * x);
  return 1.f - 2.f / (e + 1.f);
}

// ---------------- K0: geometry -> s_v0, f, su0/sd0 ----------------
__global__ __launch_bounds__(512) void k_geom(const float* __restrict__ r,
                                              const float* __restrict__ a) {
  int e = threadIdx.x;
  float rx = r[3*e], ry = r[3*e+1], rz = r[3*e+2];
  float facc = 0.f;
  #pragma unroll
  for (int at = 0; at < 16; ++at) {
    float dx = rx - a[3*at], dy = ry - a[3*at+1], dz = rz - a[3*at+2];
    float len = sqrtf(dx*dx + dy*dy + dz*dz);
    g_sv0[e*64 + 4*at + 0] = dx;
    g_sv0[e*64 + 4*at + 1] = dy;
    g_sv0[e*64 + 4*at + 2] = dz;
    g_sv0[e*64 + 4*at + 3] = len;
    facc += expf(-len);
  }
  g_f[e] = facc;
  __syncthreads();            // global writes visible within block after barrier
  if (e < 128) {
    int h = e >> 6, c = e & 63;
    float s = 0.f;
    for (int i = 0; i < 256; ++i) s += g_sv0[(h*256 + i)*64 + c];
    (h ? g_sd0 : g_su0)[c] = s * (1.f/256.f);
  }
}

// ---------------- K0b: means of p0 (4-dim geometry pairs) ----------------
__global__ __launch_bounds__(256) void k_pmean0(const float* __restrict__ r) {
  int j = blockIdx.x, t = threadIdx.x;
  float rjx = r[3*j], rjy = r[3*j+1], rjz = r[3*j+2];
  __shared__ float red[4][4];
  for (int h = 0; h < 2; ++h) {
    int i = h*256 + t;
    float dx = rjx - r[3*i], dy = rjy - r[3*i+1], dz = rjz - r[3*i+2];
    float ee = (i == j) ? 1.f : 0.f;
    float ex = dx+ee, ey = dy+ee, ez = dz+ee;
    float len = sqrtf(ex*ex + ey*ey + ez*ez);
    float v0 = dx, v1 = dy, v2 = dz, v3 = len;
    #pragma unroll
    for (int m = 1; m < 64; m <<= 1) {
      v0 += __shfl_xor(v0, m); v1 += __shfl_xor(v1, m);
      v2 += __shfl_xor(v2, m); v3 += __shfl_xor(v3, m);
    }
    if ((t & 63) == 0) {
      int wv = t >> 6;
      red[wv][0]=v0; red[wv][1]=v1; red[wv][2]=v2; red[wv][3]=v3;
    }
    __syncthreads();
    if (t == 0) {
      float* dst = h ? g_pd4 : g_pu4;
      #pragma unroll
      for (int c = 0; c < 4; ++c)
        dst[j*4 + c] = (red[0][c]+red[1][c]+red[2][c]+red[3][c]) * (1.f/256.f);
    }
    __syncthreads();
  }
}

// ---------------- p-channel update. MODE 0: from geometry; 1: load+store; 2: load only ----
template<int MODE>
__global__ __launch_bounds__(256) void k_pup(const float* __restrict__ W,
                                             const float* __restrict__ Wb,
                                             const float* __restrict__ r,
                                             int src, int dst) {
  __shared__ __align__(16) float psh[4][64];
  int t = threadIdx.x, lane = t & 63, wv = t >> 6;
  int gw = blockIdx.x*4 + wv;          // 0..4095
  int j = gw >> 3, chunk = gw & 7;
  int i0 = chunk * 64;
  float macc = 0.f;
  if (MODE == 0) {
    float w0 = W[lane], w1 = W[64+lane], w2 = W[128+lane], w3 = W[192+lane];
    float bb = Wb[lane];
    float rjx = r[3*j], rjy = r[3*j+1], rjz = r[3*j+2];
    float* pout = g_p[0];
    for (int ii = 0; ii < 64; ++ii) {
      int i = i0 + ii;
      float dx = rjx - r[3*i], dy = rjy - r[3*i+1], dz = rjz - r[3*i+2];
      float ee = (i == j) ? 1.f : 0.f;
      float ex = dx+ee, ey = dy+ee, ez = dz+ee;
      float len = sqrtf(ex*ex + ey*ey + ez*ez);
      float y = tanh_fast(bb + dx*w0 + dy*w1 + dz*w2 + len*w3);
      pout[(i*NE + j)*64 + lane] = y;
      macc += y;
    }
  } else {
    const float* pin = g_p[src];
    float* pout = g_p[dst];
    float wcol[64];
    #pragma unroll
    for (int k = 0; k < 64; ++k) wcol[k] = W[k*64 + lane];
    float bb = Wb[lane];
    for (int ii = 0; ii < 64; ++ii) {
      int i = i0 + ii;
      int base = (i*NE + j)*64;
      float x = pin[base + lane];
      psh[wv][lane] = x;
      float acc = bb;
      #pragma unroll
      for (int g = 0; g < 16; ++g) {
        float4 pv = *(const float4*)&psh[wv][4*g];   // wave-uniform broadcast reads
        acc += pv.x*wcol[4*g] + pv.y*wcol[4*g+1] + pv.z*wcol[4*g+2] + pv.w*wcol[4*g+3];
      }
      float y = tanh_fast(acc) + x;                  // residual (layers >= 1)
      if (MODE == 1) pout[base + lane] = y;
      macc += y;
    }
  }
  g_part[chunk*(NE*64) + j*64 + lane] = macc;
}

// ---------------- finalize p-means + s-means ----------------
__global__ __launch_bounds__(256) void k_reduce(int svsel) {
  int bid = blockIdx.x, t = threadIdx.x;
  if (bid < 256) {
    int idx = bid*256 + t;
    int half = idx >> 15, rem = idx & 32767;
    int j = rem >> 6, l = rem & 63;
    const float* pp = g_part + half*(4*NE*64);
    float s = pp[0*(NE*64)+j*64+l] + pp[1*(NE*64)+j*64+l]
            + pp[2*(NE*64)+j*64+l] + pp[3*(NE*64)+j*64+l];
    (half ? g_pd : g_pu)[j*64 + l] = s * (1.f/256.f);
  } else {
    int h = bid - 256;
    const float* sv = g_sv[svsel];
    float s = 0.f;
    for (int i = 0; i < 256; ++i) s += sv[(h*256 + i)*256 + t];
    (h ? g_sd : g_su)[t] = s * (1.f/256.f);
  }
}

// ---------------- generic s-channel matmul (layers / heads / orbitals) ----------------
// which: 0=layer0, 1..3=layer l, 4=head_u, 5=head_d, 6=orb_u, 7=orb_d
template<int PUK, int SVK, int MEANK>
__global__ __launch_bounds__(256) void k_smm(int which, const float* __restrict__ W,
                                             const float* __restrict__ Wb) {
  constexpr int MAINK = 2*PUK + SVK;
  __shared__ __align__(16) float wsl[MAINK*32];
  __shared__ float insl[32*(MAINK+1)];
  __shared__ float biasv[32];
  __shared__ float bred[256];
  const float *pu_p=nullptr, *pd_p=nullptr, *sv_p=nullptr, *su_p=nullptr, *sd_p=nullptr;
  const float *res_p=nullptr, *rs_p=nullptr;
  float* out_p = nullptr;
  int row0 = 0, dotanh = 1;
  switch (which) {
    case 0: pu_p=g_pu4; pd_p=g_pd4; su_p=g_su0; sd_p=g_sd0; sv_p=g_sv0; out_p=g_sv[0]; break;
    case 1: case 2: case 3:
      pu_p=g_pu; pd_p=g_pd; su_p=g_su; sd_p=g_sd;
      sv_p=g_sv[(which+1)&1]; res_p=sv_p; out_p=g_sv[which&1]; break;
    case 4: pu_p=g_pu; pd_p=g_pd; su_p=g_su; sd_p=g_sd; sv_p=g_sv[1]; out_p=g_hu; break;
    case 5: pu_p=g_pu; pd_p=g_pd; su_p=g_su; sd_p=g_sd; sv_p=g_sv[1]; out_p=g_hd; row0=256; break;
    case 6: sv_p=g_hu; out_p=g_orbu; rs_p=g_f;       dotanh=0; break;
    default: sv_p=g_hd; out_p=g_orbd; rs_p=g_f+256;  dotanh=0; break;
  }
  int t = threadIdx.x;
  int rg = blockIdx.x, cg = blockIdx.y;
  int col0 = cg * 32;
  for (int idx = t; idx < MAINK*32; idx += 256) {
    int c = idx >> 5, cl = idx & 31;
    wsl[idx] = W[(2*MEANK + c)*256 + col0 + cl];
  }
  for (int rr = 0; rr < 32; ++rr) {
    int row = row0 + rg*32 + rr;
    for (int c = t; c < MAINK; c += 256) {
      float v;
      if (c < PUK) v = pu_p[row*PUK + c];
      else if (c < 2*PUK) v = pd_p[row*PUK + (c - PUK)];
      else v = sv_p[row*SVK + (c - 2*PUK)];
      insl[rr*(MAINK+1) + c] = v;
    }
  }
  {
    int pcol = t & 31, ps = t >> 5;
    float bacc = 0.f;
    if (MEANK > 0) {
      for (int c = ps; c < MEANK; c += 8)
        bacc += su_p[c]*W[c*256 + col0 + pcol] + sd_p[c]*W[(MEANK + c)*256 + col0 + pcol];
    }
    bred[ps*32 + pcol] = bacc;
  }
  __syncthreads();
  if (t < 32) {
    float s = Wb[col0 + t];
    #pragma unroll
    for (int p8 = 0; p8 < 8; ++p8) s += bred[p8*32 + t];
    biasv[t] = s;
  }
  __syncthreads();
  int c4 = t & 7, rl = t >> 3;
  float a0 = biasv[4*c4], a1 = biasv[4*c4+1], a2 = biasv[4*c4+2], a3 = biasv[4*c4+3];
  const float* inrow = &insl[rl*(MAINK+1)];
  for (int c = 0; c < MAINK; ++c) {
    float iv = inrow[c];
    float4 wv = *(const float4*)&wsl[c*32 + 4*c4];
    a0 += iv*wv.x; a1 += iv*wv.y; a2 += iv*wv.z; a3 += iv*wv.w;
  }
  int rowA = rg*32 + rl;
  int col = col0 + 4*c4;
  if (dotanh) { a0=tanh_fast(a0); a1=tanh_fast(a1); a2=tanh_fast(a2); a3=tanh_fast(a3); }
  if (res_p) {
    float4 rv = *(const float4*)&res_p[rowA*256 + col];
    a0 += rv.x; a1 += rv.y; a2 += rv.z; a3 += rv.w;
  }
  if (rs_p) { float fsc = rs_p[rowA]; a0*=fsc; a1*=fsc; a2*=fsc; a3*=fsc; }
  float4 ov; ov.x=a0; ov.y=a1; ov.z=a2; ov.w=a3;
  *(float4*)&out_p[rowA*256 + col] = ov;
}

// ---------------- register-resident LU, 2-D tiles (v4) ----------------
// R3 lesson: no spill ever existed (FETCH was KB not MB); k_lu is LDS-issue +
// latency bound (16 waves x 16 broadcast b128 reads of the pivot row per iter).
// v4: 512 threads, each owns an 8x16 tile (rows 8*tile_r.., cols 16*tile_c..).
// Per iter per thread: 2 colbuf reads (multipliers) + 4 padded prow reads
// (6 LDS reads vs 16), 128 FMA, 2 barriers. Pivot row published once by the
// 16 owner threads into a 68-word-stride padded buffer (2-way max conflicts).
#define REP8(M) M(0) M(1) M(2) M(3) M(4) M(5) M(6) M(7)

__global__ __launch_bounds__(512, 2) void k_lu() {
  __shared__ __align__(16) float colbuf[256];
  __shared__ __align__(16) float prowbuf[16*68];     // group c at word 68c (padded)
  const float* A = (blockIdx.x == 0) ? g_orbu : g_orbd;
  int t = threadIdx.x;
  int tile_r = t >> 4;        // 0..31 -> rows 8*tile_r .. +7
  int tile_c = t & 15;        // 0..15 -> cols 16*tile_c .. +15
  int lane = t & 63;
  int br = tile_r * 8;
  int pb = tile_c * 68;
  const float4* Ap = (const float4*)(A + (tile_r*8)*256 + tile_c*16);
  // row stride = 64 float4
#define DECLROW(R) float4 M##R##_0 = Ap[R*64+0], M##R##_1 = Ap[R*64+1], \
                          M##R##_2 = Ap[R*64+2], M##R##_3 = Ap[R*64+3];
  REP8(DECLROW)
#undef DECLROW
  unsigned um = 0;            // used-mask for candidate rows 4*lane..4*lane+3
  if (tile_c == 0) {
#define INIT0(R) colbuf[br+R] = M##R##_0.x;
    REP8(INIT0)
#undef INIT0
  }
  __syncthreads();
  float logsum = 0.f;
  for (int k = 0; k < 256; ++k) {
    // ---- phase S: pivot search on colbuf (holds column k) ----
    float4 cv = *(const float4*)&colbuf[4*lane];
    unsigned b0 = (um & 1u) ? 0u : ((__float_as_uint(fabsf(cv.x)) & 0xFFFFFF00u) | (unsigned)(4*lane+0));
    unsigned b1 = (um & 2u) ? 0u : ((__float_as_uint(fabsf(cv.y)) & 0xFFFFFF00u) | (unsigned)(4*lane+1));
    unsigned b2 = (um & 4u) ? 0u : ((__float_as_uint(fabsf(cv.z)) & 0xFFFFFF00u) | (unsigned)(4*lane+2));
    unsigned b3 = (um & 8u) ? 0u : ((__float_as_uint(fabsf(cv.w)) & 0xFFFFFF00u) | (unsigned)(4*lane+3));
    unsigned bb = max(max(b0,b1), max(b2,b3));
    #pragma unroll
    for (int m = 1; m < 64; m <<= 1) {
      unsigned ob = __shfl_xor(bb, m);
      bb = ob > bb ? ob : bb;
    }
    int p = (int)(bb & 255u);
    float piv = colbuf[p];
    logsum += logf(fabsf(piv));
    if ((p >> 2) == lane) um |= 1u << (p & 3);
    if (k == 255) break;
    float rp = 1.0f / piv;
    float4 ca = *(const float4*)&colbuf[br];
    float4 cb = *(const float4*)&colbuf[br+4];
    float m0 = ca.x*rp, m1 = ca.y*rp, m2 = ca.z*rp, m3 = ca.w*rp;
    float m4 = cb.x*rp, m5 = cb.y*rp, m6 = cb.z*rp, m7 = cb.w*rp;
    // pivot-row owners publish their 16-col slice (uniform switch on p&7)
    if (tile_r == (p >> 3)) {
      switch (p & 7) {
#define PUBC(R) case R: *(float4*)&prowbuf[pb+0] = M##R##_0; *(float4*)&prowbuf[pb+4] = M##R##_1; \
                        *(float4*)&prowbuf[pb+8] = M##R##_2; *(float4*)&prowbuf[pb+12] = M##R##_3; break;
        REP8(PUBC)
#undef PUBC
      }
    }
    __syncthreads();
    // ---- phase U: rank-1 update + extract column k+1 ----
    float4 P0 = *(const float4*)&prowbuf[pb+0];
    float4 P1 = *(const float4*)&prowbuf[pb+4];
    float4 P2 = *(const float4*)&prowbuf[pb+8];
    float4 P3 = *(const float4*)&prowbuf[pb+12];
#define UPD(R) { float mr = m##R; \
  M##R##_0.x -= mr*P0.x; M##R##_0.y -= mr*P0.y; M##R##_0.z -= mr*P0.z; M##R##_0.w -= mr*P0.w; \
  M##R##_1.x -= mr*P1.x; M##R##_1.y -= mr*P1.y; M##R##_1.z -= mr*P1.z; M##R##_1.w -= mr*P1.w; \
  M##R##_2.x -= mr*P2.x; M##R##_2.y -= mr*P2.y; M##R##_2.z -= mr*P2.z; M##R##_2.w -= mr*P2.w; \
  M##R##_3.x -= mr*P3.x; M##R##_3.y -= mr*P3.y; M##R##_3.z -= mr*P3.z; M##R##_3.w -= mr*P3.w; }
    REP8(UPD)
#undef UPD
    int kn = k + 1;
    if (tile_c == (kn >> 4)) {
      switch (kn & 15) {
#define EXTC(I, G, C) case I: { colbuf[br+0]=M0_##G.C; colbuf[br+1]=M1_##G.C; \
  colbuf[br+2]=M2_##G.C; colbuf[br+3]=M3_##G.C; colbuf[br+4]=M4_##G.C; \
  colbuf[br+5]=M5_##G.C; colbuf[br+6]=M6_##G.C; colbuf[br+7]=M7_##G.C; } break;
        EXTC(0,0,x) EXTC(1,0,y) EXTC(2,0,z) EXTC(3,0,w)
        EXTC(4,1,x) EXTC(5,1,y) EXTC(6,1,z) EXTC(7,1,w)
        EXTC(8,2,x) EXTC(9,2,y) EXTC(10,2,z) EXTC(11,2,w)
        EXTC(12,3,x) EXTC(13,3,y) EXTC(14,3,z) EXTC(15,3,w)
#undef EXTC
      }
    }
    __syncthreads();
  }
  if (t == 0) g_logs[blockIdx.x] = logsum;
}

__global__ void k_final(float* out) { out[0] = g_logs[0] + g_logs[1]; }

// ---------------- launch ----------------
extern "C" void kernel_launch(void* const* d_in, const int* in_sizes, int n_in,
                              void* d_out, int out_size, void* d_ws, size_t ws_size,
                              hipStream_t stream) {
  const float* r     = (const float*)d_in[0];
  const float* a     = (const float*)d_in[1];
  const float* V0_W  = (const float*)d_in[2];
  const float* V0_b  = (const float*)d_in[3];
  const float* Vr_W  = (const float*)d_in[4];
  const float* Vr_b  = (const float*)d_in[5];
  const float* W0_W  = (const float*)d_in[6];
  const float* W0_b  = (const float*)d_in[7];
  const float* Wr_W  = (const float*)d_in[8];
  const float* Wr_b  = (const float*)d_in[9];
  const float* Vhu_W = (const float*)d_in[10];
  const float* Vhu_b = (const float*)d_in[11];
  const float* Vhd_W = (const float*)d_in[12];
  const float* Vhd_b = (const float*)d_in[13];
  const float* wu_W  = (const float*)d_in[14];
  const float* wu_b  = (const float*)d_in[15];
  const float* wd_W  = (const float*)d_in[16];
  const float* wd_b  = (const float*)d_in[17];
  float* out = (float*)d_out;

  k_geom<<<1, 512, 0, stream>>>(r, a);
  k_pmean0<<<512, 256, 0, stream>>>(r);

  // layer 0
  k_smm<4,64,64><<<dim3(16,8), 256, 0, stream>>>(0, V0_W, V0_b);
  k_pup<0><<<1024, 256, 0, stream>>>(W0_W, W0_b, r, 0, 0);
  k_reduce<<<258, 256, 0, stream>>>(0);
  // layer 1
  k_smm<64,256,256><<<dim3(16,8), 256, 0, stream>>>(1, Vr_W + 0*896*256, Vr_b + 0);
  k_pup<1><<<1024, 256, 0, stream>>>(Wr_W + 0*4096, Wr_b + 0, r, 0, 1);
  k_reduce<<<258, 256, 0, stream>>>(1);
  // layer 2
  k_smm<64,256,256><<<dim3(16,8), 256, 0, stream>>>(2, Vr_W + 1*896*256, Vr_b + 256);
  k_pup<1><<<1024, 256, 0, stream>>>(Wr_W + 1*4096, Wr_b + 64, r, 1, 0);
  k_reduce<<<258, 256, 0, stream>>>(0);
  // layer 3 (p4 not stored; only its means)
  k_smm<64,256,256><<<dim3(16,8), 256, 0, stream>>>(3, Vr_W + 2*896*256, Vr_b + 512);
  k_pup<2><<<1024, 256, 0, stream>>>(Wr_W + 2*4096, Wr_b + 128, r, 0, 0);
  k_reduce<<<258, 256, 0, stream>>>(1);
  // heads
  k_smm<64,256,256><<<dim3(8,8), 256, 0, stream>>>(4, Vhu_W, Vhu_b);
  k_smm<64,256,256><<<dim3(8,8), 256, 0, stream>>>(5, Vhd_W, Vhd_b);
  // orbitals
  k_smm<0,256,0><<<dim3(8,8), 256, 0, stream>>>(6, wu_W, wu_b);
  k_smm<0,256,0><<<dim3(8,8), 256, 0, stream>>>(7, wd_W, wd_b);
  // log|det| x2 and combine
  k_lu<<<2, 512, 0, stream>>>();
  k_final<<<1, 1, 0, stream>>>(out);
}